// Round 3
// baseline (645.444 us; speedup 1.0000x reference)
//
#include <hip/hip_runtime.h>
#include <hip/hip_bf16.h>
#include <stdint.h>

using bf16 = __hip_bfloat16;
typedef short bf16x8 __attribute__((ext_vector_type(8)));
typedef float floatx4 __attribute__((ext_vector_type(4)));

static constexpr int NODES = 2048;
static constexpr int EDGES = 32768;

// pack 8 consecutive f32 -> 8 bf16 (rne) as uint4
__device__ inline uint4 cvt8(const float* __restrict__ p) {
    const float4* f = (const float4*)p;
    float4 a = f[0], b = f[1];
    union { uint4 u; bf16 h[8]; } pk;
    pk.h[0] = __float2bfloat16(a.x); pk.h[1] = __float2bfloat16(a.y);
    pk.h[2] = __float2bfloat16(a.z); pk.h[3] = __float2bfloat16(a.w);
    pk.h[4] = __float2bfloat16(b.x); pk.h[5] = __float2bfloat16(b.y);
    pk.h[6] = __float2bfloat16(b.z); pk.h[7] = __float2bfloat16(b.w);
    return pk.u;
}

// ---------------- zero the fp32 agg buffer -------------
__global__ __launch_bounds__(256) void zero_agg(float4* __restrict__ p) {
    p[(size_t)blockIdx.x * 256 + threadIdx.x] = float4{0.f, 0.f, 0.f, 0.f};
}

// ---------------- index extraction from f32 one-hot rows ----------------
// one wave per row; row = 2048 f32 = 8 KB; up to 8 coalesced uint4 passes
// with wave-level early exit once the hot column is found.
__global__ __launch_bounds__(256) void extract_idx(
    const float* __restrict__ rel_rec, const float* __restrict__ rel_send,
    int* __restrict__ recv_idx, int* __restrict__ send_idx)
{
    const int b = blockIdx.x;          // 0..16383
    const int half = b >> 13;          // 0: rel_rec, 1: rel_send
    const int rb = b & 8191;
    const float* mat = half ? rel_send : rel_rec;
    int* out = half ? send_idx : recv_idx;
    const int w = threadIdx.x >> 6;
    const int lane = threadIdx.x & 63;
    const int row = rb * 4 + w;        // 0..32767
    if (lane == 0) out[row] = 0;       // defensive init (wave program-order precedes detect)
    const uint4* base = (const uint4*)(mat + (size_t)row * NODES);
    for (int p = 0; p < 8; ++p) {
        uint4 v = base[p * 64 + lane];
        const bool hit = (v.x | v.y | v.z | v.w) != 0u;
        if (hit) {
            int e = v.x ? 0 : (v.y ? 1 : (v.z ? 2 : 3));
            out[row] = p * 256 + lane * 4 + e;
        }
        if (__any(hit)) break;         // wave early exit: avg ~4.5/8 passes
    }
}

// ---------------- generic 128x128 MFMA GEMM (f32 in, bf16 MFMA core) -------
// C[m,n] = epilogue( sum_k A[m,k] * Bt[n,k] + bias[n] ),  Bt is f32 [N,K]
// AMODE 0: A is bf16 scratch [M,K]
// AMODE 1: A row e = concat(inputsF[sidx[e]], inputsF[ridx[e]]) f32->bf16 (K=512)
// AMODE 2: A row n = concat(inputsF[n], aggin[n]) f32->bf16 (K=512)
// EPI 0: relu, store bf16 scratch Cout[M,N]
// EPI 1: relu, atomicAdd fp32 into aggout[ridx[m]*256 + n]
// EPI 2: add f32 residual inputsF[m,n], store f32 OutF (N==256)
template<int AMODE, int EPI>
__global__ __launch_bounds__(256, 2) void gemm128(
    const bf16* __restrict__ A, const float* __restrict__ Bt,
    const float* __restrict__ bias, bf16* __restrict__ Cout,
    float* __restrict__ OutF, const float* __restrict__ inputsF,
    const int* __restrict__ sidx, const int* __restrict__ ridx,
    const float* __restrict__ aggin, float* __restrict__ aggout,
    int M, int N, int K)
{
    constexpr int BM = 128, BN = 128, BK = 32;
    __shared__ bf16 As[BM * BK];   // 8 KB
    __shared__ bf16 Bs[BN * BK];   // 8 KB
    __shared__ int sIdx[BM];
    __shared__ int rIdx[BM];

    const int t = threadIdx.x;
    const int m0 = blockIdx.y * BM;
    const int n0 = blockIdx.x * BN;

    if constexpr (AMODE == 1) {
        if (t < BM) {
            sIdx[t] = sidx[m0 + t] & (NODES - 1);   // OOB structurally impossible
            rIdx[t] = ridx[m0 + t] & (NODES - 1);
        }
        __syncthreads();
    }

    // staging: thread t covers LDS row (p*64 + t/4), 16B bf16 chunk (t%4)
    const int sr = t >> 2;
    const int sc = t & 3;

    uint4 ra[2], rb[2];

    auto loadTiles = [&](int kt) {
        const int kk = kt * BK + sc * 8;   // element column within K
#pragma unroll
        for (int p = 0; p < 2; ++p) {
            const int row = p * 64 + sr;
            if constexpr (AMODE == 0) {
                ra[p] = *(const uint4*)(A + (size_t)(m0 + row) * K + kk);
            } else if constexpr (AMODE == 1) {
                const int node = (kk < 256) ? sIdx[row] : rIdx[row];
                ra[p] = cvt8(inputsF + (size_t)node * 256 + (kk & 255));
            } else {
                const float* src = (kk < 256)
                    ? (inputsF + (size_t)(m0 + row) * 256 + kk)
                    : (aggin + (size_t)(m0 + row) * 256 + (kk - 256));
                ra[p] = cvt8(src);
            }
            rb[p] = cvt8(Bt + (size_t)(n0 + row) * K + kk);
        }
    };

    const int wv = t >> 6;
    const int lane = t & 63;
    const int wm = wv >> 1, wn = wv & 1;   // wave covers 64x64 region
    const int r16 = lane & 15, q = lane >> 4;

    floatx4 acc[4][4] = {};

    loadTiles(0);
    const int KT = K / BK;
    for (int kt = 0; kt < KT; ++kt) {
        __syncthreads();
#pragma unroll
        for (int p = 0; p < 2; ++p) {
            *(uint4*)(&As[(p * 64 + sr) * BK + sc * 8]) = ra[p];
            *(uint4*)(&Bs[(p * 64 + sr) * BK + sc * 8]) = rb[p];
        }
        __syncthreads();
        if (kt + 1 < KT) loadTiles(kt + 1);   // overlap next-tile loads with MFMA

        bf16x8 af[4], bf[4];
#pragma unroll
        for (int i = 0; i < 4; ++i)
            af[i] = *(const bf16x8*)(&As[(wm * 64 + i * 16 + r16) * BK + q * 8]);
#pragma unroll
        for (int j = 0; j < 4; ++j)
            bf[j] = *(const bf16x8*)(&Bs[(wn * 64 + j * 16 + r16) * BK + q * 8]);
#pragma unroll
        for (int i = 0; i < 4; ++i)
#pragma unroll
            for (int j = 0; j < 4; ++j)
                acc[i][j] = __builtin_amdgcn_mfma_f32_16x16x32_bf16(af[i], bf[j], acc[i][j], 0, 0, 0);
    }

    float bv[4];
#pragma unroll
    for (int j = 0; j < 4; ++j)
        bv[j] = bias[n0 + wn * 64 + j * 16 + r16];

    // C/D layout: col = lane&15, row = q*4 + r (verified m89/m91)
#pragma unroll
    for (int i = 0; i < 4; ++i) {
        const int rbase = m0 + wm * 64 + i * 16 + q * 4;
#pragma unroll
        for (int j = 0; j < 4; ++j) {
            const int gc = n0 + wn * 64 + j * 16 + r16;
#pragma unroll
            for (int r = 0; r < 4; ++r) {
                float v = acc[i][j][r] + bv[j];
                const int gr = rbase + r;
                if constexpr (EPI == 0) {
                    v = fmaxf(v, 0.0f);
                    Cout[(size_t)gr * N + gc] = __float2bfloat16(v);
                } else if constexpr (EPI == 1) {
                    v = fmaxf(v, 0.0f);
                    atomicAdd(&aggout[(size_t)(ridx[gr] & (NODES - 1)) * 256 + gc], v);
                } else {
                    OutF[(size_t)gr * 256 + gc] = inputsF[(size_t)gr * 256 + gc] + v;
                }
            }
        }
    }
}

extern "C" void kernel_launch(void* const* d_in, const int* in_sizes, int n_in,
                              void* d_out, int out_size, void* d_ws, size_t ws_size,
                              hipStream_t stream) {
    const float* inputs   = (const float*)d_in[0];
    const float* rel_rec  = (const float*)d_in[1];
    const float* rel_send = (const float*)d_in[2];
    const float* msg_W1   = (const float*)d_in[3];
    const float* msg_b1   = (const float*)d_in[4];
    const float* msg_W2   = (const float*)d_in[5];
    const float* msg_b2   = (const float*)d_in[6];
    const float* out_W1   = (const float*)d_in[7];
    const float* out_b1   = (const float*)d_in[8];
    const float* out_W2   = (const float*)d_in[9];
    const float* out_b2   = (const float*)d_in[10];
    const float* out_W3   = (const float*)d_in[11];
    const float* out_b3   = (const float*)d_in[12];

    // workspace layout (fixed part: 6.5 MB)
    char* ws = (char*)d_ws;
    int*   recv_idx = (int*)(ws + 0);            // 128 KB
    int*   send_idx = (int*)(ws + 131072);       // 128 KB
    float* agg      = (float*)(ws + 262144);     // 2 MB fp32 [2048,256]
    bf16*  g1       = (bf16*)(ws + 2359296);     // 2 MB bf16 [2048,512]
    bf16*  g2       = (bf16*)(ws + 4456448);     // 2 MB bf16 [2048,512]
    bf16*  h1       = (bf16*)(ws + 6553600);     // edge-chunk buffer [EC,512] bf16
    const size_t fixed = 6553600;

    // pick edge-chunk size from available scratch (deterministic across calls)
    int EC;
    if      (ws_size >= fixed + (size_t)32768 * 512 * 2) EC = 32768;  // 40.1 MB total
    else if (ws_size >= fixed + (size_t)8192  * 512 * 2) EC = 8192;   // 14.9 MB total
    else if (ws_size >= fixed + (size_t)2048  * 512 * 2) EC = 2048;   //  8.7 MB total
    else return;  // ws too small: fail loudly instead of faulting

    // 1) recover edge indices from f32 one-hot incidence matrices
    extract_idx<<<16384, 256, 0, stream>>>(rel_rec, rel_send, recv_idx, send_idx);

    // 2) zero the fp32 aggregation buffer (2048*256 floats = 131072 float4)
    zero_agg<<<512, 256, 0, stream>>>((float4*)agg);

    // 3+4) edge MLP, chunked over edges:
    //      h1 = relu(gather(pre_msg) @ msg_W1^T + b1)
    //      agg[recv[e]] += relu(h1 @ msg_W2^T + b2)
    for (int e0 = 0; e0 < EDGES; e0 += EC) {
        gemm128<1, 0><<<dim3(512 / 128, EC / 128), 256, 0, stream>>>(
            nullptr, msg_W1, msg_b1, h1, nullptr, inputs,
            send_idx + e0, recv_idx + e0, nullptr, nullptr, EC, 512, 512);
        gemm128<0, 1><<<dim3(256 / 128, EC / 128), 256, 0, stream>>>(
            h1, msg_W2, msg_b2, nullptr, nullptr, nullptr,
            nullptr, recv_idx + e0, nullptr, agg, EC, 256, 512);
    }

    // 5) node MLP layer 1: g1 = relu(concat(inputs, agg) @ out_W1^T + b1)
    gemm128<2, 0><<<dim3(512 / 128, NODES / 128), 256, 0, stream>>>(
        nullptr, out_W1, out_b1, g1, nullptr, inputs,
        nullptr, nullptr, agg, nullptr, NODES, 512, 512);

    // 6) node MLP layer 2: g2 = relu(g1 @ out_W2^T + b2)
    gemm128<0, 0><<<dim3(512 / 128, NODES / 128), 256, 0, stream>>>(
        g1, out_W2, out_b2, g2, nullptr, nullptr,
        nullptr, nullptr, nullptr, nullptr, NODES, 512, 512);

    // 7) node MLP layer 3 + residual: out = inputs + (g2 @ out_W3^T + b3)
    gemm128<0, 2><<<dim3(256 / 128, NODES / 128), 256, 0, stream>>>(
        g2, out_W3, out_b3, nullptr, (float*)d_out, inputs,
        nullptr, nullptr, nullptr, nullptr, NODES, 256, 512);
}

// Round 4
// 628.861 us; speedup vs baseline: 1.0264x; 1.0264x over previous
//
#include <hip/hip_runtime.h>
#include <hip/hip_bf16.h>
#include <stdint.h>

using bf16 = __hip_bfloat16;
typedef short bf16x8 __attribute__((ext_vector_type(8)));
typedef float floatx4 __attribute__((ext_vector_type(4)));

static constexpr int NODES = 2048;
static constexpr int EDGES = 32768;

// pack 8 consecutive f32 -> 8 bf16 (rne) as uint4
__device__ inline uint4 cvt8(const float* __restrict__ p) {
    const float4* f = (const float4*)p;
    float4 a = f[0], b = f[1];
    union { uint4 u; bf16 h[8]; } pk;
    pk.h[0] = __float2bfloat16(a.x); pk.h[1] = __float2bfloat16(a.y);
    pk.h[2] = __float2bfloat16(a.z); pk.h[3] = __float2bfloat16(a.w);
    pk.h[4] = __float2bfloat16(b.x); pk.h[5] = __float2bfloat16(b.y);
    pk.h[6] = __float2bfloat16(b.z); pk.h[7] = __float2bfloat16(b.w);
    return pk.u;
}

// ---------------- zero the fp32 agg buffer -------------
__global__ __launch_bounds__(256) void zero_agg(float4* __restrict__ p) {
    p[(size_t)blockIdx.x * 256 + threadIdx.x] = float4{0.f, 0.f, 0.f, 0.f};
}

// ---------------- index extraction from f32 one-hot rows ----------------
// one wave per row; row = 2048 f32 = 8 KB; up to 8 coalesced uint4 passes
// with wave-level early exit (avg ~4.5 passes -> ~288 MB total read).
__global__ __launch_bounds__(256) void extract_idx(
    const float* __restrict__ rel_rec, const float* __restrict__ rel_send,
    int* __restrict__ recv_idx, int* __restrict__ send_idx)
{
    const int b = blockIdx.x;          // 0..16383
    const int half = b >> 13;          // 0: rel_rec, 1: rel_send
    const int rb = b & 8191;
    const float* mat = half ? rel_send : rel_rec;
    int* out = half ? send_idx : recv_idx;
    const int w = threadIdx.x >> 6;
    const int lane = threadIdx.x & 63;
    const int row = rb * 4 + w;        // 0..32767
    if (lane == 0) out[row] = 0;       // defensive init
    const uint4* base = (const uint4*)(mat + (size_t)row * NODES);
    for (int p = 0; p < 8; ++p) {
        uint4 v = base[p * 64 + lane];
        const bool hit = (v.x | v.y | v.z | v.w) != 0u;
        if (hit) {
            int e = v.x ? 0 : (v.y ? 1 : (v.z ? 2 : 3));
            out[row] = p * 256 + lane * 4 + e;
        }
        if (__any(hit)) break;
    }
}

// ---------------- generic 128x128 MFMA GEMM (bf16 MFMA core) ---------------
// C[m,n] = epilogue( sum_k A[m,k] * B'[n,k] + bias[n] )
// AMODE 0: A bf16 scratch [M,K]
// AMODE 1: A f32 [M,K] (cvt to bf16 in staging)
// AMODE 2: A row n = concat(inputsF[n], aggin[n]) f32->bf16 (K=512)
// AMODE 3: A row e = relu(U[sidx[e]][k] + V[ridx[e]][k] + b1[k]) f32->bf16,
//          where U=UV[:, :512], V=UV[:, 512:1024]  (K=512)
// BMODE 0: B' = Bt f32 [N,K]
// BMODE 1: B' row n = msg_W1[n&511][ (n>>9)*256 .. +K ]  (split W1 halves)
// EPI 0: +bias, relu, store bf16 Cout[M,N]
// EPI 1: +bias, relu, atomicAdd fp32 into aggout[ridx[m]*256 + n]
// EPI 2: +bias, add f32 residual inputsF[m,n], store f32 OutF (N==256)
// EPI 3: raw f32 store OutF[M,N] (no bias)
template<int AMODE, int BMODE, int EPI>
__global__ __launch_bounds__(256, 2) void gemm128(
    const bf16* __restrict__ A, const float* __restrict__ Af,
    const float* __restrict__ Bt, const float* __restrict__ bias,
    bf16* __restrict__ Cout, float* __restrict__ OutF,
    const float* __restrict__ inputsF, const float* __restrict__ UV,
    const float* __restrict__ b1v, const int* __restrict__ sidx,
    const int* __restrict__ ridx, const float* __restrict__ aggin,
    float* __restrict__ aggout, int M, int N, int K)
{
    constexpr int BM = 128, BN = 128, BK = 32;
    __shared__ bf16 As[BM * BK];   // 8 KB
    __shared__ bf16 Bs[BN * BK];   // 8 KB
    __shared__ int sIdx[BM];
    __shared__ int rIdx[BM];

    const int t = threadIdx.x;
    const int m0 = blockIdx.y * BM;
    const int n0 = blockIdx.x * BN;

    if constexpr (AMODE == 3) {
        if (t < BM) {
            sIdx[t] = sidx[m0 + t] & (NODES - 1);
            rIdx[t] = ridx[m0 + t] & (NODES - 1);
        }
        __syncthreads();
    }

    // staging: thread t covers LDS row (p*64 + t/4), 16B bf16 chunk (t%4)
    const int sr = t >> 2;
    const int sc = t & 3;

    uint4 ra[2], rb[2];

    auto loadTiles = [&](int kt) {
        const int kk = kt * BK + sc * 8;   // element column within K
#pragma unroll
        for (int p = 0; p < 2; ++p) {
            const int row = p * 64 + sr;
            if constexpr (AMODE == 0) {
                ra[p] = *(const uint4*)(A + (size_t)(m0 + row) * K + kk);
            } else if constexpr (AMODE == 1) {
                ra[p] = cvt8(Af + (size_t)(m0 + row) * K + kk);
            } else if constexpr (AMODE == 2) {
                const float* src = (kk < 256)
                    ? (inputsF + (size_t)(m0 + row) * 256 + kk)
                    : (aggin + (size_t)(m0 + row) * 256 + (kk - 256));
                ra[p] = cvt8(src);
            } else {
                const float4* u = (const float4*)(UV + (size_t)sIdx[row] * 1024 + kk);
                const float4* v = (const float4*)(UV + (size_t)rIdx[row] * 1024 + 512 + kk);
                const float4* c = (const float4*)(b1v + kk);
                float4 u0 = u[0], u1 = u[1], v0 = v[0], v1 = v[1], c0 = c[0], c1 = c[1];
                union { uint4 q; bf16 h[8]; } pk;
                pk.h[0] = __float2bfloat16(fmaxf(u0.x + v0.x + c0.x, 0.f));
                pk.h[1] = __float2bfloat16(fmaxf(u0.y + v0.y + c0.y, 0.f));
                pk.h[2] = __float2bfloat16(fmaxf(u0.z + v0.z + c0.z, 0.f));
                pk.h[3] = __float2bfloat16(fmaxf(u0.w + v0.w + c0.w, 0.f));
                pk.h[4] = __float2bfloat16(fmaxf(u1.x + v1.x + c1.x, 0.f));
                pk.h[5] = __float2bfloat16(fmaxf(u1.y + v1.y + c1.y, 0.f));
                pk.h[6] = __float2bfloat16(fmaxf(u1.z + v1.z + c1.z, 0.f));
                pk.h[7] = __float2bfloat16(fmaxf(u1.w + v1.w + c1.w, 0.f));
                ra[p] = pk.q;
            }
            if constexpr (BMODE == 0) {
                rb[p] = cvt8(Bt + (size_t)(n0 + row) * K + kk);
            } else {
                const int n = n0 + row;
                rb[p] = cvt8(Bt + (size_t)(n & 511) * 512 + (n >> 9) * 256 + kk);
            }
        }
    };

    const int wv = t >> 6;
    const int lane = t & 63;
    const int wm = wv >> 1, wn = wv & 1;   // wave covers 64x64 region
    const int r16 = lane & 15, q = lane >> 4;

    floatx4 acc[4][4] = {};

    loadTiles(0);
    const int KT = K / BK;
    for (int kt = 0; kt < KT; ++kt) {
        __syncthreads();
#pragma unroll
        for (int p = 0; p < 2; ++p) {
            *(uint4*)(&As[(p * 64 + sr) * BK + sc * 8]) = ra[p];
            *(uint4*)(&Bs[(p * 64 + sr) * BK + sc * 8]) = rb[p];
        }
        __syncthreads();
        if (kt + 1 < KT) loadTiles(kt + 1);   // overlap next-tile loads with MFMA

        bf16x8 af[4], bfr[4];
#pragma unroll
        for (int i = 0; i < 4; ++i)
            af[i] = *(const bf16x8*)(&As[(wm * 64 + i * 16 + r16) * BK + q * 8]);
#pragma unroll
        for (int j = 0; j < 4; ++j)
            bfr[j] = *(const bf16x8*)(&Bs[(wn * 64 + j * 16 + r16) * BK + q * 8]);
#pragma unroll
        for (int i = 0; i < 4; ++i)
#pragma unroll
            for (int j = 0; j < 4; ++j)
                acc[i][j] = __builtin_amdgcn_mfma_f32_16x16x32_bf16(af[i], bfr[j], acc[i][j], 0, 0, 0);
    }

    float bv[4];
#pragma unroll
    for (int j = 0; j < 4; ++j)
        bv[j] = (EPI == 3) ? 0.f : bias[n0 + wn * 64 + j * 16 + r16];

    // C/D layout: col = lane&15, row = q*4 + r (verified m89/m91)
#pragma unroll
    for (int i = 0; i < 4; ++i) {
        const int rbase = m0 + wm * 64 + i * 16 + q * 4;
#pragma unroll
        for (int j = 0; j < 4; ++j) {
            const int gc = n0 + wn * 64 + j * 16 + r16;
#pragma unroll
            for (int r = 0; r < 4; ++r) {
                float v = acc[i][j][r] + bv[j];
                const int gr = rbase + r;
                if constexpr (EPI == 0) {
                    v = fmaxf(v, 0.0f);
                    Cout[(size_t)gr * N + gc] = __float2bfloat16(v);
                } else if constexpr (EPI == 1) {
                    v = fmaxf(v, 0.0f);
                    atomicAdd(&aggout[(size_t)rIdx[gr - m0] * 256 + gc], v);
                } else if constexpr (EPI == 2) {
                    OutF[(size_t)gr * 256 + gc] = inputsF[(size_t)gr * 256 + gc] + v;
                } else {
                    OutF[(size_t)gr * N + gc] = v;
                }
            }
        }
    }
}

extern "C" void kernel_launch(void* const* d_in, const int* in_sizes, int n_in,
                              void* d_out, int out_size, void* d_ws, size_t ws_size,
                              hipStream_t stream) {
    const float* inputs   = (const float*)d_in[0];
    const float* rel_rec  = (const float*)d_in[1];
    const float* rel_send = (const float*)d_in[2];
    const float* msg_W1   = (const float*)d_in[3];
    const float* msg_b1   = (const float*)d_in[4];
    const float* msg_W2   = (const float*)d_in[5];
    const float* msg_b2   = (const float*)d_in[6];
    const float* out_W1   = (const float*)d_in[7];
    const float* out_b1   = (const float*)d_in[8];
    const float* out_W2   = (const float*)d_in[9];
    const float* out_b2   = (const float*)d_in[10];
    const float* out_W3   = (const float*)d_in[11];
    const float* out_b3   = (const float*)d_in[12];

    // workspace layout (~15 MB total)
    char* ws = (char*)d_ws;
    int*   recv_idx = (int*)(ws + 0);            // 128 KB
    int*   send_idx = (int*)(ws + 131072);       // 128 KB
    float* agg      = (float*)(ws + 262144);     // 2 MB fp32 [2048,256]
    float* UV       = (float*)(ws + 2359296);    // 8 MB fp32 [2048,1024] (U|V)
    bf16*  g1       = (bf16*)(ws + 10747904);    // 2 MB bf16 [2048,512]
    bf16*  g2       = (bf16*)(ws + 12845056);    // 2 MB bf16 [2048,512]
    if (ws_size < (size_t)15 * 1024 * 1024) return;  // fail loudly, not fault

    // 1) recover edge indices from f32 one-hot incidence matrices
    extract_idx<<<16384, 256, 0, stream>>>(rel_rec, rel_send, recv_idx, send_idx);

    // 2) zero the fp32 aggregation buffer
    zero_agg<<<512, 256, 0, stream>>>((float4*)agg);

    // 3) UV = inputs @ [W1_left | W1_right]^T  (node space: 1.07 GFLOP,
    //    replaces the 17.2 GFLOP edge-space layer-1 GEMM)
    gemm128<1, 1, 3><<<dim3(1024 / 128, NODES / 128), 256, 0, stream>>>(
        nullptr, inputs, msg_W1, nullptr, nullptr, UV,
        nullptr, nullptr, nullptr, nullptr, nullptr, nullptr, nullptr,
        NODES, 1024, 256);

    // 4) fused edge layer-2 + scatter:
    //    agg[recv[e]] += relu( relu(U[send[e]]+V[recv[e]]+b1) @ W2^T + b2 )
    gemm128<3, 0, 1><<<dim3(256 / 128, EDGES / 128), 256, 0, stream>>>(
        nullptr, nullptr, msg_W2, msg_b2, nullptr, nullptr,
        nullptr, UV, msg_b1, send_idx, recv_idx, nullptr, agg,
        EDGES, 256, 512);

    // 5) node MLP layer 1: g1 = relu(concat(inputs, agg) @ out_W1^T + b1)
    gemm128<2, 0, 0><<<dim3(512 / 128, NODES / 128), 256, 0, stream>>>(
        nullptr, nullptr, out_W1, out_b1, g1, nullptr,
        inputs, nullptr, nullptr, nullptr, nullptr, agg, nullptr,
        NODES, 512, 512);

    // 6) node MLP layer 2: g2 = relu(g1 @ out_W2^T + b2)
    gemm128<0, 0, 0><<<dim3(512 / 128, NODES / 128), 256, 0, stream>>>(
        g1, nullptr, out_W2, out_b2, g2, nullptr,
        nullptr, nullptr, nullptr, nullptr, nullptr, nullptr, nullptr,
        NODES, 512, 512);

    // 7) node MLP layer 3 + residual: out = inputs + (g2 @ out_W3^T + b3)
    gemm128<0, 0, 2><<<dim3(256 / 128, NODES / 128), 256, 0, stream>>>(
        g2, nullptr, out_W3, out_b3, nullptr, (float*)d_out,
        inputs, nullptr, nullptr, nullptr, nullptr, nullptr, nullptr,
        NODES, 256, 512);
}